// Round 1
// baseline (425.119 us; speedup 1.0000x reference)
//
#include <hip/hip_runtime.h>
#include <math.h>

// Problem constants
constexpr int CB = 2;           // batch
constexpr int CS = 2048;        // seq
constexpr int CE = 64;          // embed per head
constexpr int CH = 8;           // heads
constexpr int CBH = CB * CH;    // 16
constexpr int CBHS = CBH * CS;  // 32768
constexpr float EPS = 1e-5f;

__device__ inline float wave_reduce_sum(float v) {
  v += __shfl_xor(v, 1, 64);
  v += __shfl_xor(v, 2, 64);
  v += __shfl_xor(v, 4, 64);
  v += __shfl_xor(v, 8, 64);
  v += __shfl_xor(v, 16, 64);
  v += __shfl_xor(v, 32, 64);
  return v;
}

__device__ inline float f4get(const float4& v, int j) {
  return j == 0 ? v.x : j == 1 ? v.y : j == 2 ? v.z : v.w;
}

// ---------------- Kernel 1: LayerNorm (bias-free) ----------------
// one wave per row of 64; grid = B*S/4 blocks of 256
__global__ __launch_bounds__(256) void k_ln(const float* __restrict__ x,
                                            const float* __restrict__ ln_w,
                                            float* __restrict__ xn) {
  int row = blockIdx.x * 4 + (threadIdx.x >> 6);
  int e = threadIdx.x & 63;
  float v = x[row * CE + e];
  float mu = wave_reduce_sum(v) * (1.0f / CE);
  float d = v - mu;
  float var = wave_reduce_sum(d * d) * (1.0f / CE);
  xn[row * CE + e] = d * rsqrtf(var + EPS) * ln_w[e];
}

// ---------------- Kernel 2: per-head QKV projections ----------------
// block = 256 threads handles one (b,h) x 64-row tile. W_q/W_k/W_v[h] + xn tile in LDS.
// Layout out: Q[((b*H+h)*S + s)*E + f]
__global__ __launch_bounds__(256) void k_qkv(const float* __restrict__ xn,
                                             const float* __restrict__ Wq,
                                             const float* __restrict__ Wk,
                                             const float* __restrict__ Wv,
                                             float* __restrict__ Q,
                                             float* __restrict__ K,
                                             float* __restrict__ V) {
  __shared__ float wq[CE * CE];
  __shared__ float wk[CE * CE];
  __shared__ float wv[CE * CE];
  __shared__ float xs[64 * CE];
  int n = blockIdx.x;
  int bh = n >> 5;   // 0..15
  int st = n & 31;   // s-tile
  int h = bh & (CH - 1);
  int b = bh >> 3;
  int t = threadIdx.x;
  const float* wqg = Wq + h * CE * CE;
  const float* wkg = Wk + h * CE * CE;
  const float* wvg = Wv + h * CE * CE;
  const float* xg = xn + (b * CS + st * 64) * CE;
#pragma unroll
  for (int m = 0; m < 4; ++m) {
    int fi = m * 256 + t;  // float4 index, 1024 total = 4096 floats
    *(float4*)&wq[fi * 4] = *(const float4*)&wqg[fi * 4];
    *(float4*)&wk[fi * 4] = *(const float4*)&wkg[fi * 4];
    *(float4*)&wv[fi * 4] = *(const float4*)&wvg[fi * 4];
    *(float4*)&xs[fi * 4] = *(const float4*)&xg[fi * 4];
  }
  __syncthreads();
  int w = t >> 6, f = t & 63;
  for (int grp = 0; grp < 2; ++grp) {
    int r0 = w * 16 + grp * 8;
    float qa[8], ka[8], va[8];
#pragma unroll
    for (int r = 0; r < 8; ++r) { qa[r] = 0.f; ka[r] = 0.f; va[r] = 0.f; }
    for (int e4 = 0; e4 < 16; ++e4) {
      float4 xv[8];
#pragma unroll
      for (int r = 0; r < 8; ++r) xv[r] = *(float4*)&xs[(r0 + r) * CE + e4 * 4];  // LDS broadcast
#pragma unroll
      for (int j = 0; j < 4; ++j) {
        int e = e4 * 4 + j;
        float a = wq[e * CE + f];
        float bb = wk[e * CE + f];
        float c = wv[e * CE + f];
#pragma unroll
        for (int r = 0; r < 8; ++r) {
          float xe = f4get(xv[r], j);
          qa[r] += xe * a;
          ka[r] += xe * bb;
          va[r] += xe * c;
        }
      }
    }
    int base = (bh * CS + st * 64 + r0) * CE + f;
#pragma unroll
    for (int r = 0; r < 8; ++r) {
      Q[base + r * CE] = qa[r];
      K[base + r * CE] = ka[r];
      V[base + r * CE] = va[r];
    }
  }
}

// ---------------- Kernel 2b: row squared-norms of Q and K ----------------
__global__ __launch_bounds__(256) void k_rowsq(const float* __restrict__ Q,
                                               const float* __restrict__ K,
                                               float* __restrict__ q2,
                                               float* __restrict__ k2) {
  int row = blockIdx.x * 4 + (threadIdx.x >> 6);
  int e = threadIdx.x & 63;
  const float* src;
  float* dst;
  int r;
  if (row < CBHS) { src = Q; dst = q2; r = row; }
  else            { src = K; dst = k2; r = row - CBHS; }
  float v = src[r * CE + e];
  float s = wave_reduce_sum(v * v);
  if (e == 0) dst[r] = s;
}

// ---------------- Kernel 3: fused causal RBF attention ----------------
// grid = 512 blocks: bh = n&15, u = n>>4, qt = zig(u) so co-resident blocks balance.
// 64x64 q-tile, loop kt<=qt over 64-wide k-tiles. No softmax normalization needed.
__global__ __launch_bounds__(256) void k_attn(const float* __restrict__ Q,
                                              const float* __restrict__ K,
                                              const float* __restrict__ V,
                                              const float* __restrict__ q2,
                                              const float* __restrict__ k2,
                                              const float* __restrict__ gamma,
                                              float* __restrict__ attnout) {
  __shared__ float Qs[64 * 65];  // pad 65: phase-1 row reads land on distinct banks
  __shared__ float Ks[64 * 65];
  __shared__ float Vs[64 * 64];  // phase-2 reads are lane-consecutive: no pad needed
  __shared__ float Ss[64 * 68];  // pad 68: keeps 16B alignment for b128 broadcast reads
  __shared__ float q2s[64];
  __shared__ float k2s[64];
  int n = blockIdx.x;
  int bh = n & 15;
  int u = n >> 4;
  int qt = (u < 16) ? u : (47 - u);  // zig: pairs (u, u+16) -> (qt, 31-qt), const total work
  int h = bh & 7, b = bh >> 3;
  int t = threadIdx.x;
  float scale = gamma[h] * 0.125f;  // gamma / sqrt(E)

  // load Q tile + q2
  const float* Qg = Q + (bh * CS + qt * 64) * CE;
#pragma unroll
  for (int m = 0; m < 4; ++m) {
    int fi = m * 256 + t;
    int row = fi >> 4, c4 = (fi & 15) * 4;
    float4 qv = *(const float4*)&Qg[row * CE + c4];
    Qs[row * 65 + c4 + 0] = qv.x;
    Qs[row * 65 + c4 + 1] = qv.y;
    Qs[row * 65 + c4 + 2] = qv.z;
    Qs[row * 65 + c4 + 3] = qv.w;
  }
  if (t < 64) q2s[t] = q2[bh * CS + qt * 64 + t];

  float acc[16];
#pragma unroll
  for (int i = 0; i < 16; ++i) acc[i] = 0.f;
  int ib = t >> 6, e = t & 63;          // phase-2 mapping
  int i0 = (t >> 4) * 4, j0 = (t & 15) * 4;  // phase-1 mapping (16x16 grid of 4x4)

  for (int kt = 0; kt <= qt; ++kt) {
    __syncthreads();  // protect Ks/Vs/Ss from previous iteration's readers
    const float* Kg = K + (bh * CS + kt * 64) * CE;
    const float* Vg = V + (bh * CS + kt * 64) * CE;
#pragma unroll
    for (int m = 0; m < 4; ++m) {
      int fi = m * 256 + t;
      int row = fi >> 4, c4 = (fi & 15) * 4;
      float4 kv = *(const float4*)&Kg[row * CE + c4];
      Ks[row * 65 + c4 + 0] = kv.x;
      Ks[row * 65 + c4 + 1] = kv.y;
      Ks[row * 65 + c4 + 2] = kv.z;
      Ks[row * 65 + c4 + 3] = kv.w;
      *(float4*)&Vs[row * 64 + c4] = *(const float4*)&Vg[row * CE + c4];
    }
    if (t < 64) k2s[t] = k2[bh * CS + kt * 64 + t];
    __syncthreads();

    // phase 1: scores tile -> Ss
    float qk[4][4];
#pragma unroll
    for (int a = 0; a < 4; ++a)
#pragma unroll
      for (int bb = 0; bb < 4; ++bb) qk[a][bb] = 0.f;
#pragma unroll 4
    for (int ee = 0; ee < 64; ++ee) {
      float qa[4], kb[4];
#pragma unroll
      for (int a = 0; a < 4; ++a) qa[a] = Qs[(i0 + a) * 65 + ee];
#pragma unroll
      for (int bb = 0; bb < 4; ++bb) kb[bb] = Ks[(j0 + bb) * 65 + ee];
#pragma unroll
      for (int a = 0; a < 4; ++a)
#pragma unroll
        for (int bb = 0; bb < 4; ++bb) qk[a][bb] += qa[a] * kb[bb];
    }
    int gi0 = qt * 64 + i0, gj0 = kt * 64 + j0;
#pragma unroll
    for (int a = 0; a < 4; ++a) {
      float4 sv;
      float q2v = q2s[i0 + a];
#pragma unroll
      for (int bb = 0; bb < 4; ++bb) {
        float sq = q2v + k2s[j0 + bb] - 2.0f * qk[a][bb];
        float val = __expf(-scale * sq);
        float m = (gj0 + bb <= gi0 + a) ? val : 0.0f;
        if (bb == 0) sv.x = m; else if (bb == 1) sv.y = m; else if (bb == 2) sv.z = m; else sv.w = m;
      }
      *(float4*)&Ss[(i0 + a) * 68 + j0] = sv;
    }
    __syncthreads();

    // phase 2: acc[i][e] += Ss[i][j] * Vs[j][e]
#pragma unroll 4
    for (int j4 = 0; j4 < 16; ++j4) {
      float v0 = Vs[(j4 * 4 + 0) * 64 + e];
      float v1 = Vs[(j4 * 4 + 1) * 64 + e];
      float v2 = Vs[(j4 * 4 + 2) * 64 + e];
      float v3 = Vs[(j4 * 4 + 3) * 64 + e];
#pragma unroll
      for (int ii = 0; ii < 16; ++ii) {
        float4 s4 = *(float4*)&Ss[(ib * 16 + ii) * 68 + j4 * 4];  // wave-uniform broadcast
        acc[ii] += s4.x * v0 + s4.y * v1 + s4.z * v2 + s4.w * v3;
      }
    }
  }

  // write attn out in [B,S,H*E] layout for the projection
#pragma unroll
  for (int ii = 0; ii < 16; ++ii) {
    int srow = qt * 64 + ib * 16 + ii;
    attnout[(b * CS + srow) * (CH * CE) + h * CE + e] = acc[ii];
  }
}

// ---------------- Kernel 4: output projection out = attn @ Wo^T ----------------
// block = 256 handles 32 rows; g-chunked LDS staging of Wo^T.
__global__ __launch_bounds__(256) void k_proj(const float* __restrict__ attn,
                                              const float* __restrict__ Wo,
                                              float* __restrict__ out) {
  __shared__ float wt[128 * 65];  // WoT chunk [g][f]
  __shared__ float at[32 * 128];  // attn rows chunk
  int t = threadIdx.x;
  int row0 = blockIdx.x * 32;
  int f = t & 63, rg = t >> 6;
  float acc[8];
#pragma unroll
  for (int r = 0; r < 8; ++r) acc[r] = 0.f;
  for (int gc = 0; gc < 4; ++gc) {
    __syncthreads();
#pragma unroll
    for (int m = 0; m < 8; ++m) {
      int fi = m * 256 + t;         // 2048 float4 = 64x128
      int fr = fi >> 5;             // f row 0..63
      int gg = (fi & 31) * 4;
      float4 wv = *(const float4*)&Wo[fr * 512 + gc * 128 + gg];
      wt[(gg + 0) * 65 + fr] = wv.x;
      wt[(gg + 1) * 65 + fr] = wv.y;
      wt[(gg + 2) * 65 + fr] = wv.z;
      wt[(gg + 3) * 65 + fr] = wv.w;
    }
#pragma unroll
    for (int m = 0; m < 4; ++m) {
      int fi = m * 256 + t;         // 1024 float4 = 32x128
      int r = fi >> 5;
      int gg = (fi & 31) * 4;
      *(float4*)&at[r * 128 + gg] = *(const float4*)&attn[(row0 + r) * 512 + gc * 128 + gg];
    }
    __syncthreads();
#pragma unroll 4
    for (int g4 = 0; g4 < 32; ++g4) {
      float w0 = wt[(g4 * 4 + 0) * 65 + f];
      float w1 = wt[(g4 * 4 + 1) * 65 + f];
      float w2 = wt[(g4 * 4 + 2) * 65 + f];
      float w3 = wt[(g4 * 4 + 3) * 65 + f];
#pragma unroll
      for (int r = 0; r < 8; ++r) {
        float4 av = *(float4*)&at[(rg * 8 + r) * 128 + g4 * 4];  // wave-uniform broadcast
        acc[r] += av.x * w0 + av.y * w1 + av.z * w2 + av.w * w3;
      }
    }
  }
#pragma unroll
  for (int r = 0; r < 8; ++r) out[(row0 + rg * 8 + r) * 64 + f] = acc[r];
}

extern "C" void kernel_launch(void* const* d_in, const int* in_sizes, int n_in,
                              void* d_out, int out_size, void* d_ws, size_t ws_size,
                              hipStream_t stream) {
  const float* x     = (const float*)d_in[0];
  const float* ln_w  = (const float*)d_in[1];
  const float* Wq    = (const float*)d_in[2];
  const float* Wk    = (const float*)d_in[3];
  const float* Wv    = (const float*)d_in[4];
  const float* Wo    = (const float*)d_in[5];
  const float* gamma = (const float*)d_in[6];
  float* out = (float*)d_out;

  // workspace layout (floats): xn | Q | K | V | q2 | k2 | attnout  (~35 MB)
  float* xn = (float*)d_ws;
  float* Qb = xn + 262144;
  float* Kb = Qb + 2097152;
  float* Vb = Kb + 2097152;
  float* q2 = Vb + 2097152;
  float* k2 = q2 + 32768;
  float* at = k2 + 32768;

  hipLaunchKernelGGL(k_ln,    dim3(1024),  dim3(256), 0, stream, x, ln_w, xn);
  hipLaunchKernelGGL(k_qkv,   dim3(512),   dim3(256), 0, stream, xn, Wq, Wk, Wv, Qb, Kb, Vb);
  hipLaunchKernelGGL(k_rowsq, dim3(16384), dim3(256), 0, stream, Qb, Kb, q2, k2);
  hipLaunchKernelGGL(k_attn,  dim3(512),   dim3(256), 0, stream, Qb, Kb, Vb, q2, k2, gamma, at);
  hipLaunchKernelGGL(k_proj,  dim3(128),   dim3(256), 0, stream, at, Wo, out);
}

// Round 2
// 75.575 us; speedup vs baseline: 5.6251x; 5.6251x over previous
//
#include <hip/hip_runtime.h>
#include <math.h>

typedef __attribute__((ext_vector_type(8))) short bf8;    // 8 x bf16 (bit pattern)
typedef __attribute__((ext_vector_type(4))) short s4v;    // 4 x bf16 (8B store)
typedef __attribute__((ext_vector_type(16))) float f16v;  // MFMA 32x32 accum
typedef __attribute__((ext_vector_type(4))) float f4v;

constexpr int CS = 2048;
constexpr float EPS = 1e-5f;
constexpr float LOG2E = 1.44269504088896f;

static __device__ inline short f2bf(float x) {
  union { float f; unsigned u; } v; v.f = x;
  unsigned r = (v.u + 0x7FFFu + ((v.u >> 16) & 1u)) >> 16;  // RNE
  return (short)r;
}
static __device__ inline float red32(float v) {  // sum within 32-lane halves
  v += __shfl_xor(v, 1, 64); v += __shfl_xor(v, 2, 64);
  v += __shfl_xor(v, 4, 64); v += __shfl_xor(v, 8, 64);
  v += __shfl_xor(v, 16, 64);
  return v;
}
static __device__ inline float red64(float v) {
  v = red32(v); v += __shfl_xor(v, 32, 64);
  return v;
}

// ---------------- prep: transpose W_{q,k,v} per head -> bf16 [h][f][e]; cast Wo -> bf16 ----------------
__global__ __launch_bounds__(256) void k_prep(const float* __restrict__ Wq, const float* __restrict__ Wk,
                                              const float* __restrict__ Wv, const float* __restrict__ Wo,
                                              short* __restrict__ WtQ, short* __restrict__ WtK,
                                              short* __restrict__ WtV, short* __restrict__ Wob) {
  int blk = blockIdx.x, t = threadIdx.x;
  if (blk < 24) {
    __shared__ float tile[64][65];
    int w = blk >> 3, h = blk & 7;
    const float* src = (w == 0 ? Wq : w == 1 ? Wk : Wv) + h * 4096;
    short* dst = (w == 0 ? WtQ : w == 1 ? WtK : WtV) + h * 4096;
#pragma unroll
    for (int m = 0; m < 4; ++m) {
      int fi = m * 256 + t;
      int row = fi >> 4, c4 = (fi & 15) * 4;
      f4v v = *(const f4v*)&src[row * 64 + c4];
      tile[row][c4] = v.x; tile[row][c4 + 1] = v.y; tile[row][c4 + 2] = v.z; tile[row][c4 + 3] = v.w;
    }
    __syncthreads();
#pragma unroll
    for (int m = 0; m < 16; ++m) {
      int o = m * 256 + t;
      int f = o >> 6, e = o & 63;
      dst[f * 64 + e] = f2bf(tile[e][f]);   // Wt[f][e] = W[e][f]
    }
  } else {
    int base = (blk - 24) * 4096;
#pragma unroll
    for (int m = 0; m < 16; ++m) {
      int o = base + m * 256 + t;
      Wob[o] = f2bf(Wo[o]);
    }
  }
}

// ---------------- LayerNorm -> bf16 ----------------
__global__ __launch_bounds__(256) void k_ln(const float* __restrict__ x, const float* __restrict__ ln_w,
                                            short* __restrict__ xnb) {
  int row = blockIdx.x * 4 + (threadIdx.x >> 6);
  int e = threadIdx.x & 63;
  float v = x[row * 64 + e];
  float mu = red64(v) * (1.f / 64.f);
  float d = v - mu;
  float var = red64(d * d) * (1.f / 64.f);
  xnb[row * 64 + e] = f2bf(d * rsqrtf(var + EPS) * ln_w[e]);
}

// ---------------- QKV projections (MFMA) + q2/k2 folding ----------------
// outputs: Qb,Kb bf16 [bh][s][e]; Vt bf16 [bh][e][s] pre-scaled by exp(-g*k2/8); aq f32 [bh][s]
__global__ __launch_bounds__(256) void k_qkv(const short* __restrict__ xnb,
                                             const short* __restrict__ WtQ, const short* __restrict__ WtK,
                                             const short* __restrict__ WtV, const float* __restrict__ gamma,
                                             short* __restrict__ Qb, short* __restrict__ Kb,
                                             short* __restrict__ Vt, float* __restrict__ aqg) {
  __shared__ float q2p[2][64];
  __shared__ float k2p[2][64];
  int blk = blockIdx.x;
  int bh = blk & 15, st = blk >> 4;
  int b = bh >> 3, h = bh & 7;
  int t = threadIdx.x, wid = t >> 6, lane = t & 63;
  int l31 = lane & 31, g = lane >> 5;
  int sh = wid >> 1, fh = wid & 1;
  int f = fh * 32 + l31;

  bf8 af[4];
  int arow = (b * CS + st * 64 + sh * 32 + l31) * 64;
#pragma unroll
  for (int ks = 0; ks < 4; ++ks) af[ks] = *(const bf8*)&xnb[arow + ks * 16 + g * 8];
  float gh = gamma[h];
  float cgk = -gh * 0.125f * LOG2E;  // -gamma/8 in log2 domain

  // ---- Q ----
  f16v cq; for (int i = 0; i < 16; ++i) cq[i] = 0.f;
#pragma unroll
  for (int ks = 0; ks < 4; ++ks) {
    bf8 bw = *(const bf8*)&WtQ[h * 4096 + f * 64 + ks * 16 + g * 8];
    cq = __builtin_amdgcn_mfma_f32_32x32x16_bf16(af[ks], bw, cq, 0, 0, 0);
  }
#pragma unroll
  for (int r = 0; r < 16; ++r) {
    int rl = sh * 32 + (r & 3) + 8 * (r >> 2) + 4 * g;
    float val = cq[r];
    Qb[(bh * CS + st * 64 + rl) * 64 + f] = f2bf(val);
    float p = red32(val * val);
    if (l31 == 0) q2p[fh][rl] = p;
  }
  // ---- K ----
  f16v ck; for (int i = 0; i < 16; ++i) ck[i] = 0.f;
#pragma unroll
  for (int ks = 0; ks < 4; ++ks) {
    bf8 bw = *(const bf8*)&WtK[h * 4096 + f * 64 + ks * 16 + g * 8];
    ck = __builtin_amdgcn_mfma_f32_32x32x16_bf16(af[ks], bw, ck, 0, 0, 0);
  }
#pragma unroll
  for (int r = 0; r < 16; ++r) {
    int rl = sh * 32 + (r & 3) + 8 * (r >> 2) + 4 * g;
    float val = ck[r];
    Kb[(bh * CS + st * 64 + rl) * 64 + f] = f2bf(val);
    float p = red32(val * val);
    if (l31 == 0) k2p[fh][rl] = p;
  }
  // ---- V ----
  f16v cv; for (int i = 0; i < 16; ++i) cv[i] = 0.f;
#pragma unroll
  for (int ks = 0; ks < 4; ++ks) {
    bf8 bw = *(const bf8*)&WtV[h * 4096 + f * 64 + ks * 16 + g * 8];
    cv = __builtin_amdgcn_mfma_f32_32x32x16_bf16(af[ks], bw, cv, 0, 0, 0);
  }
  __syncthreads();
#pragma unroll
  for (int m = 0; m < 4; ++m) {
    s4v pk;
#pragma unroll
    for (int ii = 0; ii < 4; ++ii) {
      int rl = sh * 32 + ii + 8 * m + 4 * g;
      float k2t = k2p[0][rl] + k2p[1][rl];
      float bk = exp2f(cgk * k2t);
      pk[ii] = f2bf(cv[m * 4 + ii] * bk);
    }
    int scol = st * 64 + sh * 32 + 8 * m + 4 * g;
    *(s4v*)&Vt[(bh * 64 + f) * CS + scol] = pk;   // transposed, scaled
  }
  if (t < 64) {
    float q2t = q2p[0][t] + q2p[1][t];
    aqg[bh * CS + st * 64 + t] = exp2f(cgk * q2t);
  }
}

// ---------------- fused causal RBF attention (MFMA) ----------------
// T = K·Q^T (scores transposed), S = exp(g/4·qk) to LDS bf16, out^T = V'^T·S^T accumulated in regs.
__global__ __launch_bounds__(256) void k_attn(const short* __restrict__ Qb, const short* __restrict__ Kb,
                                              const short* __restrict__ Vtg, const float* __restrict__ aqg,
                                              const float* __restrict__ gamma, short* __restrict__ attnB) {
  __shared__ short KsL[2 * 4096];   // [buf][row(k) 64][e 64] XOR-swizzled, bf16
  __shared__ short VsL[2 * 4096];   // [buf][row(e) 64][s 64] XOR-swizzled, bf16 (V' transposed)
  __shared__ short SsL[4096];       // [q 64][k 64] XOR-swizzled, bf16
  int i = blockIdx.x;
  int bh = ((i & 7) << 1) | ((i >> 3) & 1);   // 2 bh per XCD -> K/V' tiles stay in that XCD's L2
  int u = i >> 4;
  int qt = (u < 16) ? u : 47 - u;             // zig: co-resident pair (u,u+16) sums to 33 ktiles
  int b = bh >> 3, h = bh & 7;
  int t = threadIdx.x, wid = t >> 6, lane = t & 63;
  int l31 = lane & 31, g = lane >> 5;
  int qh = wid >> 1, kh = wid & 1;            // QK roles; PV uses eh = kh
  int KT = qt + 1;
  float cg = gamma[h] * 0.25f * LOG2E;        // +gamma/4 in log2 domain

  // Q held in registers as B-frags for the whole task
  bf8 qf[4];
  int qrow = (bh * CS + qt * 64 + qh * 32 + l31) * 64;
#pragma unroll
  for (int ks = 0; ks < 4; ++ks) qf[ks] = *(const bf8*)&Qb[qrow + ks * 16 + g * 8];

  int srow0 = t >> 3, sch = t & 7;            // staging: thread covers rows srow0, srow0+32
  int swz = (l31 & 7) << 3;                   // row XOR swizzle (ushort units) for frag reads
  int q = qh * 32 + l31;

  f16v oacc; for (int r = 0; r < 16; ++r) oacc[r] = 0.f;

  // prologue: stage kt=0 into buf 0
  {
#pragma unroll
    for (int c = 0; c < 2; ++c) {
      int row = c * 32 + srow0;
      bf8 kv = *(const bf8*)&Kb[(bh * CS + row) * 64 + sch * 8];
      bf8 vv = *(const bf8*)&Vtg[(bh * 64 + row) * CS + sch * 8];
      int off = row * 64 + ((sch * 8) ^ ((row & 7) << 3));
      *(bf8*)&KsL[off] = kv;
      *(bf8*)&VsL[off] = vv;
    }
  }
  __syncthreads();

  int buf = 0;
  for (int kt = 0; kt < KT; ++kt) {
    // issue kt+1 global loads early (hide L2/HBM latency under QK compute)
    bf8 kr0, kr1, vr0, vr1;
    bool more = (kt + 1 < KT);
    if (more) {
      int r0 = srow0, r1 = 32 + srow0;
      kr0 = *(const bf8*)&Kb[(bh * CS + (kt + 1) * 64 + r0) * 64 + sch * 8];
      kr1 = *(const bf8*)&Kb[(bh * CS + (kt + 1) * 64 + r1) * 64 + sch * 8];
      vr0 = *(const bf8*)&Vtg[(bh * 64 + r0) * CS + (kt + 1) * 64 + sch * 8];
      vr1 = *(const bf8*)&Vtg[(bh * 64 + r1) * CS + (kt + 1) * 64 + sch * 8];
    }
    // ---- QK: T = K·Q^T (wave: k-half kh, q-half qh) ----
    f16v ct; for (int r = 0; r < 16; ++r) ct[r] = 0.f;
    int kbase = buf * 4096 + (kh * 32 + l31) * 64;
#pragma unroll
    for (int ks = 0; ks < 4; ++ks) {
      bf8 ak = *(const bf8*)&KsL[kbase + ((ks * 16 + g * 8) ^ swz)];
      ct = __builtin_amdgcn_mfma_f32_32x32x16_bf16(ak, qf[ks], ct, 0, 0, 0);
    }
    // exp + causal mask + pack to bf16 S
    bool diag = (kt == qt);
#pragma unroll
    for (int m = 0; m < 4; ++m) {
      s4v sp;
#pragma unroll
      for (int ii = 0; ii < 4; ++ii) {
        int kl = kh * 32 + ii + 8 * m + 4 * g;
        float sv = exp2f(cg * ct[m * 4 + ii]);
        if (diag && kl > q) sv = 0.f;
        sp[ii] = f2bf(sv);
      }
      int koff = kh * 32 + 8 * m + 4 * g;
      *(s4v*)&SsL[q * 64 + (koff ^ swz)] = sp;
    }
    // write kt+1 staged regs into the other buffer
    if (more) {
      int r0 = srow0, r1 = 32 + srow0;
      int o0 = (buf ^ 1) * 4096 + r0 * 64 + ((sch * 8) ^ ((r0 & 7) << 3));
      int o1 = (buf ^ 1) * 4096 + r1 * 64 + ((sch * 8) ^ ((r1 & 7) << 3));
      *(bf8*)&KsL[o0] = kr0; *(bf8*)&KsL[o1] = kr1;
      *(bf8*)&VsL[o0] = vr0; *(bf8*)&VsL[o1] = vr1;
    }
    __syncthreads();
    // ---- PV: out^T += V'(A, rows e) · S^T(B, cols q) ----
    int vbase = buf * 4096 + (kh * 32 + l31) * 64;   // eh = kh
#pragma unroll
    for (int ks = 0; ks < 4; ++ks) {
      bf8 av = *(const bf8*)&VsL[vbase + ((ks * 16 + g * 8) ^ swz)];
      bf8 bs = *(const bf8*)&SsL[q * 64 + ((ks * 16 + g * 8) ^ swz)];
      oacc = __builtin_amdgcn_mfma_f32_32x32x16_bf16(av, bs, oacc, 0, 0, 0);
    }
    __syncthreads();
    buf ^= 1;
  }
  // epilogue: multiply by aq = exp(-g*q2/8), store bf16 [b][s][h*64+e]
  int s = qt * 64 + q;
  float aqv = aqg[bh * CS + s];
#pragma unroll
  for (int m = 0; m < 4; ++m) {
    s4v ov;
#pragma unroll
    for (int ii = 0; ii < 4; ++ii) ov[ii] = f2bf(oacc[m * 4 + ii] * aqv);
    *(s4v*)&attnB[(b * CS + s) * 512 + h * 64 + (kh * 32 + 8 * m + 4 * g)] = ov;
  }
}

// ---------------- output projection (MFMA, k-split + LDS reduce) ----------------
__global__ __launch_bounds__(256) void k_proj(const short* __restrict__ attnB, const short* __restrict__ Wob,
                                              float* __restrict__ out) {
  __shared__ float red[2][32][64];
  int blk = blockIdx.x, t = threadIdx.x;
  int r0 = blk * 32;
  int wid = t >> 6, lane = t & 63, l31 = lane & 31, g = lane >> 5;
  int fh = wid & 1, kh = wid >> 1;
  f16v c; for (int i = 0; i < 16; ++i) c[i] = 0.f;
  int arow = (r0 + l31) * 512;
  int brow = (fh * 32 + l31) * 512;
#pragma unroll
  for (int ks = 0; ks < 16; ++ks) {
    int k0 = kh * 256 + ks * 16 + g * 8;
    bf8 a = *(const bf8*)&attnB[arow + k0];
    bf8 bw = *(const bf8*)&Wob[brow + k0];
    c = __builtin_amdgcn_mfma_f32_32x32x16_bf16(a, bw, c, 0, 0, 0);
  }
#pragma unroll
  for (int r = 0; r < 16; ++r) {
    int row = (r & 3) + 8 * (r >> 2) + 4 * g;
    red[kh][row][fh * 32 + l31] = c[r];
  }
  __syncthreads();
#pragma unroll
  for (int cc = 0; cc < 2; ++cc) {
    int flat = (t * 2 + cc) * 4;
    int row = flat >> 6, f = flat & 63;
    f4v a = *(f4v*)&red[0][row][f];
    f4v bsum = *(f4v*)&red[1][row][f];
    f4v sum = a + bsum;
    *(f4v*)&out[(r0 + row) * 64 + f] = sum;
  }
}

extern "C" void kernel_launch(void* const* d_in, const int* in_sizes, int n_in,
                              void* d_out, int out_size, void* d_ws, size_t ws_size,
                              hipStream_t stream) {
  const float* x     = (const float*)d_in[0];
  const float* ln_w  = (const float*)d_in[1];
  const float* Wq    = (const float*)d_in[2];
  const float* Wk    = (const float*)d_in[3];
  const float* Wv    = (const float*)d_in[4];
  const float* Wo    = (const float*)d_in[5];
  const float* gamma = (const float*)d_in[6];
  float* out = (float*)d_out;

  char* w = (char*)d_ws;
  short* xnb   = (short*)w;                                   // 512 KB
  short* Qb    = (short*)(w + 524288);                        // 4 MB
  short* Kb    = (short*)(w + 524288 + 4194304);              // 4 MB
  short* Vt    = (short*)(w + 524288 + 2 * 4194304);          // 4 MB
  float* aqg   = (float*)(w + 524288 + 3 * 4194304);          // 128 KB
  short* attnB = (short*)(w + 524288 + 3 * 4194304 + 131072); // 4 MB
  short* WtQ   = (short*)(w + 524288 + 4 * 4194304 + 131072);
  short* WtK   = WtQ + 32768;
  short* WtV   = WtK + 32768;
  short* Wob   = WtV + 32768;

  hipLaunchKernelGGL(k_prep, dim3(32),   dim3(256), 0, stream, Wq, Wk, Wv, Wo, WtQ, WtK, WtV, Wob);
  hipLaunchKernelGGL(k_ln,   dim3(1024), dim3(256), 0, stream, x, ln_w, xnb);
  hipLaunchKernelGGL(k_qkv,  dim3(512),  dim3(256), 0, stream, xnb, WtQ, WtK, WtV, gamma, Qb, Kb, Vt, aqg);
  hipLaunchKernelGGL(k_attn, dim3(512),  dim3(256), 0, stream, Qb, Kb, Vt, aqg, gamma, attnB);
  hipLaunchKernelGGL(k_proj, dim3(128),  dim3(256), 0, stream, attnB, Wob, out);
}

// Round 3
// 71.665 us; speedup vs baseline: 5.9320x; 1.0546x over previous
//
#include <hip/hip_runtime.h>
#include <math.h>

typedef __attribute__((ext_vector_type(8))) short bf8;    // 8 x bf16 (bit pattern)
typedef __attribute__((ext_vector_type(4))) short s4v;    // 4 x bf16 (8B store)
typedef __attribute__((ext_vector_type(16))) float f16v;  // MFMA 32x32 accum
typedef __attribute__((ext_vector_type(4))) float f4v;
typedef __attribute__((ext_vector_type(4))) int i4v;

constexpr int CS = 2048;
constexpr float EPS = 1e-5f;
constexpr float LOG2E = 1.44269504088896f;

static __device__ inline short f2bf(float x) {
  union { float f; unsigned u; } v; v.f = x;
  unsigned r = (v.u + 0x7FFFu + ((v.u >> 16) & 1u)) >> 16;  // RNE
  return (short)r;
}
static __device__ inline unsigned cvt_pk_bf16(float lo, float hi) {
  unsigned d;
  asm("v_cvt_pk_bf16_f32 %0, %1, %2" : "=v"(d) : "v"(lo), "v"(hi));
  return d;
}
static __device__ inline float red32(float v) {  // sum within 32-lane halves
  v += __shfl_xor(v, 1, 64); v += __shfl_xor(v, 2, 64);
  v += __shfl_xor(v, 4, 64); v += __shfl_xor(v, 8, 64);
  v += __shfl_xor(v, 16, 64);
  return v;
}

// ---------------- prep: transpose W_{q,k,v} per head -> bf16 [h][f][e]; cast Wo -> bf16 ----------------
__global__ __launch_bounds__(256) void k_prep(const float* __restrict__ Wq, const float* __restrict__ Wk,
                                              const float* __restrict__ Wv, const float* __restrict__ Wo,
                                              short* __restrict__ WtQ, short* __restrict__ WtK,
                                              short* __restrict__ WtV, short* __restrict__ Wob) {
  int blk = blockIdx.x, t = threadIdx.x;
  if (blk < 24) {
    __shared__ float tile[64][65];
    int w = blk >> 3, h = blk & 7;
    const float* src = (w == 0 ? Wq : w == 1 ? Wk : Wv) + h * 4096;
    short* dst = (w == 0 ? WtQ : w == 1 ? WtK : WtV) + h * 4096;
#pragma unroll
    for (int m = 0; m < 4; ++m) {
      int fi = m * 256 + t;
      int row = fi >> 4, c4 = (fi & 15) * 4;
      f4v v = *(const f4v*)&src[row * 64 + c4];
      tile[row][c4] = v.x; tile[row][c4 + 1] = v.y; tile[row][c4 + 2] = v.z; tile[row][c4 + 3] = v.w;
    }
    __syncthreads();
#pragma unroll
    for (int m = 0; m < 16; ++m) {
      int o = m * 256 + t;
      int f = o >> 6, e = o & 63;
      dst[f * 64 + e] = f2bf(tile[e][f]);   // Wt[f][e] = W[e][f]
    }
  } else {
    int base = (blk - 24) * 4096;
#pragma unroll
    for (int m = 0; m < 16; ++m) {
      int o = base + m * 256 + t;
      Wob[o] = f2bf(Wo[o]);
    }
  }
}

// ---------------- fused LN + QKV projections (MFMA) + q2/k2 folding ----------------
// outputs: Qb,Kb bf16 [bh][s][e]; Vt bf16 [bh][e][s] pre-scaled by exp(-g*k2/8); aq f32 [bh][s]
__global__ __launch_bounds__(256) void k_qkv(const float* __restrict__ x, const float* __restrict__ ln_w,
                                             const short* __restrict__ WtQ, const short* __restrict__ WtK,
                                             const short* __restrict__ WtV, const float* __restrict__ gamma,
                                             short* __restrict__ Qb, short* __restrict__ Kb,
                                             short* __restrict__ Vt, float* __restrict__ aqg) {
  __shared__ float q2p[2][64];
  __shared__ float k2p[2][64];
  int blk = blockIdx.x;
  int bh = blk & 15, st = blk >> 4;
  int b = bh >> 3, h = bh & 7;
  int t = threadIdx.x, wid = t >> 6, lane = t & 63;
  int l31 = lane & 31, g = lane >> 5;
  int sh = wid >> 1, fh = wid & 1;
  int f = fh * 32 + l31;

  // ---- in-register LayerNorm over this lane's row (lane holds 32 of 64 elems) ----
  int row = b * CS + st * 64 + sh * 32 + l31;
  f4v xv[8];
#pragma unroll
  for (int ks = 0; ks < 4; ++ks) {
    xv[2 * ks]     = *(const f4v*)&x[row * 64 + ks * 16 + g * 8];
    xv[2 * ks + 1] = *(const f4v*)&x[row * 64 + ks * 16 + g * 8 + 4];
  }
  float s = 0.f;
#pragma unroll
  for (int m = 0; m < 8; ++m) s += xv[m].x + xv[m].y + xv[m].z + xv[m].w;
  s += __shfl_xor(s, 32, 64);
  float mu = s * (1.f / 64.f);
  float vs = 0.f;
#pragma unroll
  for (int m = 0; m < 8; ++m) {
#pragma unroll
    for (int j = 0; j < 4; ++j) { float d = xv[m][j] - mu; vs += d * d; }
  }
  vs += __shfl_xor(vs, 32, 64);
  float rs = rsqrtf(vs * (1.f / 64.f) + EPS);
  bf8 af[4];
#pragma unroll
  for (int ks = 0; ks < 4; ++ks) {
    f4v lw0 = *(const f4v*)&ln_w[ks * 16 + g * 8];
    f4v lw1 = *(const f4v*)&ln_w[ks * 16 + g * 8 + 4];
#pragma unroll
    for (int j = 0; j < 4; ++j) {
      af[ks][j]     = f2bf((xv[2 * ks][j] - mu) * rs * lw0[j]);
      af[ks][j + 4] = f2bf((xv[2 * ks + 1][j] - mu) * rs * lw1[j]);
    }
  }
  float gh = gamma[h];
  float cgk = -gh * 0.125f * LOG2E;  // -gamma/8 in log2 domain

  // ---- Q ----
  f16v cq; for (int i = 0; i < 16; ++i) cq[i] = 0.f;
#pragma unroll
  for (int ks = 0; ks < 4; ++ks) {
    bf8 bw = *(const bf8*)&WtQ[h * 4096 + f * 64 + ks * 16 + g * 8];
    cq = __builtin_amdgcn_mfma_f32_32x32x16_bf16(af[ks], bw, cq, 0, 0, 0);
  }
#pragma unroll
  for (int r = 0; r < 16; ++r) {
    int rl = sh * 32 + (r & 3) + 8 * (r >> 2) + 4 * g;
    float val = cq[r];
    Qb[(bh * CS + st * 64 + rl) * 64 + f] = f2bf(val);
    float p = red32(val * val);
    if (l31 == 0) q2p[fh][rl] = p;
  }
  // ---- K ----
  f16v ck; for (int i = 0; i < 16; ++i) ck[i] = 0.f;
#pragma unroll
  for (int ks = 0; ks < 4; ++ks) {
    bf8 bw = *(const bf8*)&WtK[h * 4096 + f * 64 + ks * 16 + g * 8];
    ck = __builtin_amdgcn_mfma_f32_32x32x16_bf16(af[ks], bw, ck, 0, 0, 0);
  }
#pragma unroll
  for (int r = 0; r < 16; ++r) {
    int rl = sh * 32 + (r & 3) + 8 * (r >> 2) + 4 * g;
    float val = ck[r];
    Kb[(bh * CS + st * 64 + rl) * 64 + f] = f2bf(val);
    float p = red32(val * val);
    if (l31 == 0) k2p[fh][rl] = p;
  }
  // ---- V ----
  f16v cv; for (int i = 0; i < 16; ++i) cv[i] = 0.f;
#pragma unroll
  for (int ks = 0; ks < 4; ++ks) {
    bf8 bw = *(const bf8*)&WtV[h * 4096 + f * 64 + ks * 16 + g * 8];
    cv = __builtin_amdgcn_mfma_f32_32x32x16_bf16(af[ks], bw, cv, 0, 0, 0);
  }
  __syncthreads();
#pragma unroll
  for (int m = 0; m < 4; ++m) {
    s4v pk;
#pragma unroll
    for (int ii = 0; ii < 4; ++ii) {
      int rl = sh * 32 + ii + 8 * m + 4 * g;
      float k2t = k2p[0][rl] + k2p[1][rl];
      float bk = exp2f(cgk * k2t);
      pk[ii] = f2bf(cv[m * 4 + ii] * bk);
    }
    int scol = st * 64 + sh * 32 + 8 * m + 4 * g;
    *(s4v*)&Vt[(bh * 64 + f) * CS + scol] = pk;   // transposed, scaled
  }
  if (t < 64) {
    float q2t = q2p[0][t] + q2p[1][t];
    aqg[bh * CS + st * 64 + t] = exp2f(cgk * q2t);
  }
}

// ---------------- fused causal RBF attention (MFMA, S fully in registers) ----------------
// T = K·Q^T; S = exp(g/4·qk) packed to bf16 in-reg (cvt_pk + shfl_xor partner exchange);
// each wave accumulates out^T over its 32-k strip for BOTH e-halves; epilogue LDS-reduces kh pairs.
__global__ __launch_bounds__(256) void k_attn(const short* __restrict__ Qb, const short* __restrict__ Kb,
                                              const short* __restrict__ Vtg, const float* __restrict__ aqg,
                                              const float* __restrict__ gamma, short* __restrict__ attnB) {
  __shared__ short KsL[2 * 4096];   // [buf][row(k) 64][e 64] XOR-swizzled, bf16
  __shared__ short VsL[2 * 4096];   // [buf][row(e) 64][s 64] XOR-swizzled, bf16 (V' transposed)
  __shared__ float redf[64 * 65];   // epilogue cross-wave reduce [e][q]
  int i = blockIdx.x;
  int xcd = i & 7, rank = i >> 3;
  int c = rank >> 1, half = rank & 1;
  int bh = (xcd << 1) | half;          // 2 bh per XCD -> K/V' stay in that XCD's L2
  int qt = half ? (31 - c) : c;        // consecutive-in-XCD blocks sum to 33 ktiles (CU-balanced)
  int b = bh >> 3, h = bh & 7;
  int t = threadIdx.x, wid = t >> 6, lane = t & 63;
  int l31 = lane & 31, g = lane >> 5;
  int qh = wid >> 1, kh = wid & 1;
  float cg = gamma[h] * 0.25f * LOG2E; // +gamma/4 in log2 domain
  int swz = (l31 & 7) << 3;            // row XOR swizzle (ushort units) for frag reads

  // Q held in registers as B-frags for the whole task
  bf8 qf[4];
  int qrow = (bh * CS + qt * 64 + qh * 32 + l31) * 64;
#pragma unroll
  for (int ks = 0; ks < 4; ++ks) qf[ks] = *(const bf8*)&Qb[qrow + ks * 16 + g * 8];

  int srow0 = t >> 3, sch = t & 7;     // staging: thread covers rows srow0, srow0+32

  // prologue: stage kt=0 into buf 0
#pragma unroll
  for (int cc = 0; cc < 2; ++cc) {
    int row = cc * 32 + srow0;
    bf8 kv = *(const bf8*)&Kb[(bh * CS + row) * 64 + sch * 8];
    bf8 vv = *(const bf8*)&Vtg[(bh * 64 + row) * CS + sch * 8];
    int off = row * 64 + ((sch * 8) ^ ((row & 7) << 3));
    *(bf8*)&KsL[off] = kv;
    *(bf8*)&VsL[off] = vv;
  }
  f16v oa0, oa1;
#pragma unroll
  for (int r = 0; r < 16; ++r) { oa0[r] = 0.f; oa1[r] = 0.f; }
  __syncthreads();

  int buf = 0;
  for (int kt = 0; kt <= qt; ++kt) {
    // issue kt+1 global loads early (latency hides under this iteration's compute)
    bf8 kr0, kr1, vr0, vr1;
    bool more = kt < qt;
    if (more) {
      int r0 = srow0, r1 = srow0 + 32;
      kr0 = *(const bf8*)&Kb[(bh * CS + (kt + 1) * 64 + r0) * 64 + sch * 8];
      kr1 = *(const bf8*)&Kb[(bh * CS + (kt + 1) * 64 + r1) * 64 + sch * 8];
      vr0 = *(const bf8*)&Vtg[(bh * 64 + r0) * CS + (kt + 1) * 64 + sch * 8];
      vr1 = *(const bf8*)&Vtg[(bh * 64 + r1) * CS + (kt + 1) * 64 + sch * 8];
    }
    bool diag = (kt == qt);
    bool active = !(diag && kh == 1 && qh == 0);  // fully-masked wave skips compute
    if (active) {
      // ---- QK: T = K·Q^T over this wave's 32-k strip ----
      f16v ct;
#pragma unroll
      for (int r = 0; r < 16; ++r) ct[r] = 0.f;
      int kbase = buf * 4096 + (kh * 32 + l31) * 64;
#pragma unroll
      for (int ks = 0; ks < 4; ++ks) {
        bf8 ak = *(const bf8*)&KsL[kbase + ((ks * 16 + g * 8) ^ swz)];
        ct = __builtin_amdgcn_mfma_f32_32x32x16_bf16(ak, qf[ks], ct, 0, 0, 0);
      }
      // ---- exp + causal mask + in-register bf16 pack ----
      bool needmask = diag && (kh == qh);
      unsigned pkA[4], pkB[4];
#pragma unroll
      for (int m = 0; m < 4; ++m) {
        float sv[4];
#pragma unroll
        for (int ii = 0; ii < 4; ++ii) {
          int kloc = ii + 8 * m + 4 * g;
          float ev = exp2f(cg * ct[4 * m + ii]);
          if (needmask && kloc > l31) ev = 0.f;
          sv[ii] = ev;
        }
        pkA[m] = cvt_pk_bf16(sv[0], sv[1]);
        pkB[m] = cvt_pk_bf16(sv[2], sv[3]);
      }
      unsigned sA[4], sB[4];
#pragma unroll
      for (int m = 0; m < 4; ++m) {
        sA[m] = (unsigned)__shfl_xor((int)pkA[m], 32, 64);
        sB[m] = (unsigned)__shfl_xor((int)pkB[m], 32, 64);
      }
      // ---- PV: out^T[e][q] += V'^T[e][k-strip]·S^T[k-strip][q], both e-halves ----
#pragma unroll
      for (int ks2 = 0; ks2 < 2; ++ks2) {
        i4v w;
        w.x = g ? (int)sA[2 * ks2 + 1] : (int)pkA[2 * ks2];
        w.y = g ? (int)sB[2 * ks2 + 1] : (int)pkB[2 * ks2];
        w.z = g ? (int)pkA[2 * ks2 + 1] : (int)sA[2 * ks2];
        w.w = g ? (int)pkB[2 * ks2 + 1] : (int)sB[2 * ks2];
        bf8 bs = *(bf8*)&w;
        int kcol = kh * 32 + ks2 * 16 + g * 8;
        bf8 av0 = *(const bf8*)&VsL[buf * 4096 + l31 * 64 + (kcol ^ swz)];
        oa0 = __builtin_amdgcn_mfma_f32_32x32x16_bf16(av0, bs, oa0, 0, 0, 0);
        bf8 av1 = *(const bf8*)&VsL[buf * 4096 + (32 + l31) * 64 + (kcol ^ swz)];
        oa1 = __builtin_amdgcn_mfma_f32_32x32x16_bf16(av1, bs, oa1, 0, 0, 0);
      }
    }
    // write kt+1 staged regs into the other buffer (prev readers of buf^1 done at last barrier)
    if (more) {
      int r0 = srow0, r1 = srow0 + 32;
      int o0 = (buf ^ 1) * 4096 + r0 * 64 + ((sch * 8) ^ ((r0 & 7) << 3));
      int o1 = (buf ^ 1) * 4096 + r1 * 64 + ((sch * 8) ^ ((r1 & 7) << 3));
      *(bf8*)&KsL[o0] = kr0; *(bf8*)&KsL[o1] = kr1;
      *(bf8*)&VsL[o0] = vr0; *(bf8*)&VsL[o1] = vr1;
    }
    __syncthreads();   // single barrier per k-tile
    buf ^= 1;
  }

  // ---- epilogue: reduce kh=0 + kh=1 partials in LDS, apply aq, coalesced bf16 store ----
  if (kh == 0) {
#pragma unroll
    for (int r = 0; r < 16; ++r) {
      int e = (r & 3) + 8 * (r >> 2) + 4 * g;
      redf[e * 65 + qh * 32 + l31] = oa0[r];
      redf[(e + 32) * 65 + qh * 32 + l31] = oa1[r];
    }
  }
  __syncthreads();
  if (kh == 1) {
#pragma unroll
    for (int r = 0; r < 16; ++r) {
      int e = (r & 3) + 8 * (r >> 2) + 4 * g;
      redf[e * 65 + qh * 32 + l31] += oa0[r];
      redf[(e + 32) * 65 + qh * 32 + l31] += oa1[r];
    }
  }
  __syncthreads();
  int q = t >> 2, e0 = (t & 3) * 16;
  float aqv = aqg[bh * CS + qt * 64 + q];
  short tmp[16];
#pragma unroll
  for (int jj = 0; jj < 16; ++jj) tmp[jj] = f2bf(redf[(e0 + jj) * 65 + q] * aqv);
  int obase = (b * CS + qt * 64 + q) * 512 + h * 64 + e0;
  *(bf8*)&attnB[obase] = *(bf8*)&tmp[0];
  *(bf8*)&attnB[obase + 8] = *(bf8*)&tmp[8];
}

// ---------------- output projection (MFMA, k-split + LDS reduce) ----------------
__global__ __launch_bounds__(256) void k_proj(const short* __restrict__ attnB, const short* __restrict__ Wob,
                                              float* __restrict__ out) {
  __shared__ float red[2][32][64];
  int blk = blockIdx.x, t = threadIdx.x;
  int r0 = blk * 32;
  int wid = t >> 6, lane = t & 63, l31 = lane & 31, g = lane >> 5;
  int fh = wid & 1, kh = wid >> 1;
  f16v c; for (int i = 0; i < 16; ++i) c[i] = 0.f;
  int arow = (r0 + l31) * 512;
  int brow = (fh * 32 + l31) * 512;
#pragma unroll
  for (int ks = 0; ks < 16; ++ks) {
    int k0 = kh * 256 + ks * 16 + g * 8;
    bf8 a = *(const bf8*)&attnB[arow + k0];
    bf8 bw = *(const bf8*)&Wob[brow + k0];
    c = __builtin_amdgcn_mfma_f32_32x32x16_bf16(a, bw, c, 0, 0, 0);
  }
#pragma unroll
  for (int r = 0; r < 16; ++r) {
    int row = (r & 3) + 8 * (r >> 2) + 4 * g;
    red[kh][row][fh * 32 + l31] = c[r];
  }
  __syncthreads();
#pragma unroll
  for (int cc = 0; cc < 2; ++cc) {
    int flat = (t * 2 + cc) * 4;
    int row = flat >> 6, f = flat & 63;
    f4v a = *(f4v*)&red[0][row][f];
    f4v bsum = *(f4v*)&red[1][row][f];
    f4v sum = a + bsum;
    *(f4v*)&out[(r0 + row) * 64 + f] = sum;
  }
}

extern "C" void kernel_launch(void* const* d_in, const int* in_sizes, int n_in,
                              void* d_out, int out_size, void* d_ws, size_t ws_size,
                              hipStream_t stream) {
  const float* x     = (const float*)d_in[0];
  const float* ln_w  = (const float*)d_in[1];
  const float* Wq    = (const float*)d_in[2];
  const float* Wk    = (const float*)d_in[3];
  const float* Wv    = (const float*)d_in[4];
  const float* Wo    = (const float*)d_in[5];
  const float* gamma = (const float*)d_in[6];
  float* out = (float*)d_out;

  char* w = (char*)d_ws;
  short* Qb    = (short*)w;                                   // 4 MB
  short* Kb    = (short*)(w + 4194304);                       // 4 MB
  short* Vt    = (short*)(w + 2 * 4194304);                   // 4 MB
  float* aqg   = (float*)(w + 3 * 4194304);                   // 128 KB
  short* attnB = (short*)(w + 3 * 4194304 + 131072);          // 4 MB
  short* WtQ   = (short*)(w + 4 * 4194304 + 131072);
  short* WtK   = WtQ + 32768;
  short* WtV   = WtK + 32768;
  short* Wob   = WtV + 32768;

  hipLaunchKernelGGL(k_prep, dim3(32),  dim3(256), 0, stream, Wq, Wk, Wv, Wo, WtQ, WtK, WtV, Wob);
  hipLaunchKernelGGL(k_qkv,  dim3(512), dim3(256), 0, stream, x, ln_w, WtQ, WtK, WtV, gamma, Qb, Kb, Vt, aqg);
  hipLaunchKernelGGL(k_attn, dim3(512), dim3(256), 0, stream, Qb, Kb, Vt, aqg, gamma, attnB);
  hipLaunchKernelGGL(k_proj, dim3(128), dim3(256), 0, stream, attnB, Wob, out);
}

// Round 4
// 66.278 us; speedup vs baseline: 6.4142x; 1.0813x over previous
//
#include <hip/hip_runtime.h>
#include <math.h>

typedef __attribute__((ext_vector_type(8))) short bf8;    // 8 x bf16 (bit pattern)
typedef __attribute__((ext_vector_type(4))) short s4v;    // 4 x bf16 (8B store)
typedef __attribute__((ext_vector_type(16))) float f16v;  // MFMA 32x32 accum
typedef __attribute__((ext_vector_type(4))) float f4v;
typedef __attribute__((ext_vector_type(4))) int i4v;

constexpr int CS = 2048;
constexpr float EPS = 1e-5f;
constexpr float LOG2E = 1.44269504088896f;

static __device__ inline short f2bf(float x) {
  union { float f; unsigned u; } v; v.f = x;
  unsigned r = (v.u + 0x7FFFu + ((v.u >> 16) & 1u)) >> 16;  // RNE
  return (short)r;
}
static __device__ inline unsigned cvt_pk_bf16(float lo, float hi) {
  unsigned d;
  asm("v_cvt_pk_bf16_f32 %0, %1, %2" : "=v"(d) : "v"(lo), "v"(hi));
  return d;
}
static __device__ inline float red32(float v) {  // sum within 32-lane halves
  v += __shfl_xor(v, 1, 64); v += __shfl_xor(v, 2, 64);
  v += __shfl_xor(v, 4, 64); v += __shfl_xor(v, 8, 64);
  v += __shfl_xor(v, 16, 64);
  return v;
}

// ---------------- prep: transpose W_{q,k,v} per head -> bf16 [h][f][e]; cast Wo -> bf16 ----------------
__global__ __launch_bounds__(256) void k_prep(const float* __restrict__ Wq, const float* __restrict__ Wk,
                                              const float* __restrict__ Wv, const float* __restrict__ Wo,
                                              short* __restrict__ WtQ, short* __restrict__ WtK,
                                              short* __restrict__ WtV, short* __restrict__ Wob) {
  int blk = blockIdx.x, t = threadIdx.x;
  if (blk < 24) {
    __shared__ float tile[64][65];
    int w = blk >> 3, h = blk & 7;
    const float* src = (w == 0 ? Wq : w == 1 ? Wk : Wv) + h * 4096;
    short* dst = (w == 0 ? WtQ : w == 1 ? WtK : WtV) + h * 4096;
#pragma unroll
    for (int m = 0; m < 4; ++m) {
      int fi = m * 256 + t;
      int row = fi >> 4, c4 = (fi & 15) * 4;
      f4v v = *(const f4v*)&src[row * 64 + c4];
      tile[row][c4] = v.x; tile[row][c4 + 1] = v.y; tile[row][c4 + 2] = v.z; tile[row][c4 + 3] = v.w;
    }
    __syncthreads();
#pragma unroll
    for (int m = 0; m < 16; ++m) {
      int o = m * 256 + t;
      int f = o >> 6, e = o & 63;
      dst[f * 64 + e] = f2bf(tile[e][f]);   // Wt[f][e] = W[e][f]
    }
  } else {
    int base = (blk - 24) * 4096;
#pragma unroll
    for (int m = 0; m < 16; ++m) {
      int o = base + m * 256 + t;
      Wob[o] = f2bf(Wo[o]);
    }
  }
}

// ---------------- fused LN + QKV projections (MFMA) + q2/k2 folding ----------------
// outputs: Qb,Kb bf16 [bh][s][e]; Vt bf16 [bh][e][s] pre-scaled by exp(-g*k2/8); aq f32 [bh][s]
__global__ __launch_bounds__(256) void k_qkv(const float* __restrict__ x, const float* __restrict__ ln_w,
                                             const short* __restrict__ WtQ, const short* __restrict__ WtK,
                                             const short* __restrict__ WtV, const float* __restrict__ gamma,
                                             short* __restrict__ Qb, short* __restrict__ Kb,
                                             short* __restrict__ Vt, float* __restrict__ aqg) {
  __shared__ float q2p[2][64];
  __shared__ float k2p[2][64];
  int blk = blockIdx.x;
  int bh = blk & 15, st = blk >> 4;
  int b = bh >> 3, h = bh & 7;
  int t = threadIdx.x, wid = t >> 6, lane = t & 63;
  int l31 = lane & 31, g = lane >> 5;
  int sh = wid >> 1, fh = wid & 1;
  int f = fh * 32 + l31;

  // ---- in-register LayerNorm over this lane's row (lane holds 32 of 64 elems) ----
  int row = b * CS + st * 64 + sh * 32 + l31;
  f4v xv[8];
#pragma unroll
  for (int ks = 0; ks < 4; ++ks) {
    xv[2 * ks]     = *(const f4v*)&x[row * 64 + ks * 16 + g * 8];
    xv[2 * ks + 1] = *(const f4v*)&x[row * 64 + ks * 16 + g * 8 + 4];
  }
  float s = 0.f;
#pragma unroll
  for (int m = 0; m < 8; ++m) s += xv[m].x + xv[m].y + xv[m].z + xv[m].w;
  s += __shfl_xor(s, 32, 64);
  float mu = s * (1.f / 64.f);
  float vs = 0.f;
#pragma unroll
  for (int m = 0; m < 8; ++m) {
#pragma unroll
    for (int j = 0; j < 4; ++j) { float d = xv[m][j] - mu; vs += d * d; }
  }
  vs += __shfl_xor(vs, 32, 64);
  float rs = rsqrtf(vs * (1.f / 64.f) + EPS);
  bf8 af[4];
#pragma unroll
  for (int ks = 0; ks < 4; ++ks) {
    f4v lw0 = *(const f4v*)&ln_w[ks * 16 + g * 8];
    f4v lw1 = *(const f4v*)&ln_w[ks * 16 + g * 8 + 4];
#pragma unroll
    for (int j = 0; j < 4; ++j) {
      af[ks][j]     = f2bf((xv[2 * ks][j] - mu) * rs * lw0[j]);
      af[ks][j + 4] = f2bf((xv[2 * ks + 1][j] - mu) * rs * lw1[j]);
    }
  }
  float gh = gamma[h];
  float cgk = -gh * 0.125f * LOG2E;  // -gamma/8 in log2 domain

  // ---- Q ----
  f16v cq; for (int i = 0; i < 16; ++i) cq[i] = 0.f;
#pragma unroll
  for (int ks = 0; ks < 4; ++ks) {
    bf8 bw = *(const bf8*)&WtQ[h * 4096 + f * 64 + ks * 16 + g * 8];
    cq = __builtin_amdgcn_mfma_f32_32x32x16_bf16(af[ks], bw, cq, 0, 0, 0);
  }
#pragma unroll
  for (int r = 0; r < 16; ++r) {
    int rl = sh * 32 + (r & 3) + 8 * (r >> 2) + 4 * g;
    float val = cq[r];
    Qb[(bh * CS + st * 64 + rl) * 64 + f] = f2bf(val);
    float p = red32(val * val);
    if (l31 == 0) q2p[fh][rl] = p;
  }
  // ---- K ----
  f16v ck; for (int i = 0; i < 16; ++i) ck[i] = 0.f;
#pragma unroll
  for (int ks = 0; ks < 4; ++ks) {
    bf8 bw = *(const bf8*)&WtK[h * 4096 + f * 64 + ks * 16 + g * 8];
    ck = __builtin_amdgcn_mfma_f32_32x32x16_bf16(af[ks], bw, ck, 0, 0, 0);
  }
#pragma unroll
  for (int r = 0; r < 16; ++r) {
    int rl = sh * 32 + (r & 3) + 8 * (r >> 2) + 4 * g;
    float val = ck[r];
    Kb[(bh * CS + st * 64 + rl) * 64 + f] = f2bf(val);
    float p = red32(val * val);
    if (l31 == 0) k2p[fh][rl] = p;
  }
  // ---- V ----
  f16v cv; for (int i = 0; i < 16; ++i) cv[i] = 0.f;
#pragma unroll
  for (int ks = 0; ks < 4; ++ks) {
    bf8 bw = *(const bf8*)&WtV[h * 4096 + f * 64 + ks * 16 + g * 8];
    cv = __builtin_amdgcn_mfma_f32_32x32x16_bf16(af[ks], bw, cv, 0, 0, 0);
  }
  __syncthreads();
#pragma unroll
  for (int m = 0; m < 4; ++m) {
    s4v pk;
#pragma unroll
    for (int ii = 0; ii < 4; ++ii) {
      int rl = sh * 32 + ii + 8 * m + 4 * g;
      float k2t = k2p[0][rl] + k2p[1][rl];
      float bk = exp2f(cgk * k2t);
      pk[ii] = f2bf(cv[m * 4 + ii] * bk);
    }
    int scol = st * 64 + sh * 32 + 8 * m + 4 * g;
    *(s4v*)&Vt[(bh * 64 + f) * CS + scol] = pk;   // transposed, scaled
  }
  if (t < 64) {
    float q2t = q2p[0][t] + q2p[1][t];
    aqg[bh * CS + st * 64 + t] = exp2f(cgk * q2t);
  }
}

// ---------------- fused causal RBF attention (MFMA, split-k, S fully in registers) ----------------
// Block = (bh, qt, half): half 0 covers kt in [0,kmid), half 1 covers [kmid, qt+1).
// Sweep-model-balanced: within an XCD, CU j's 4 sweeps sum to exactly 33 k-tiles.
__global__ __launch_bounds__(256) void k_attn(const short* __restrict__ Qb, const short* __restrict__ Kb,
                                              const short* __restrict__ Vtg, const float* __restrict__ aqg,
                                              const float* __restrict__ gamma,
                                              short* __restrict__ P0, short* __restrict__ P1) {
  __shared__ __align__(16) char smem[32768];
  short* KsL = (short*)smem;              // [2][64][64] bf16, XOR-swizzled
  short* VsL = (short*)(smem + 16384);    // [2][64][64] bf16, XOR-swizzled (V' transposed)
  float* redf = (float*)smem;             // epilogue alias [64][65] f32 (K/V dead by then)

  int i = blockIdx.x;
  int xcd = i & 7, r = i >> 3;
  int sweep = r >> 5, j = r & 31;
  int bh, qt, half;
  if      (sweep == 0) { bh = xcd * 2;     qt = j;      half = 0; }
  else if (sweep == 1) { bh = xcd * 2;     qt = 31 - j; half = 1; }
  else if (sweep == 2) { bh = xcd * 2 + 1; qt = j;      half = 1; }
  else                 { bh = xcd * 2 + 1; qt = 31 - j; half = 0; }
  int kmid = (qt + 2) >> 1;
  int k0 = half ? kmid : 0;
  int k1 = half ? (qt + 1) : kmid;

  int b = bh >> 3, h = bh & 7;
  int t = threadIdx.x, wid = t >> 6, lane = t & 63;
  int l31 = lane & 31, g = lane >> 5;
  int qh = wid >> 1, kh = wid & 1;
  float cg = gamma[h] * 0.25f * LOG2E;    // +gamma/4 in log2 domain
  int swz = (l31 & 7) << 3;               // row XOR swizzle (ushort units) for frag reads

  // Q held in registers as B-frags for the whole task
  bf8 qf[4];
  int qrow = (bh * CS + qt * 64 + qh * 32 + l31) * 64;
#pragma unroll
  for (int ks = 0; ks < 4; ++ks) qf[ks] = *(const bf8*)&Qb[qrow + ks * 16 + g * 8];

  int srow0 = t >> 3, sch = t & 7;        // staging: thread covers rows srow0, srow0+32

  // prologue: stage kt=k0 into buf 0 (harmless if k0==k1: tile k0<=16 always exists)
#pragma unroll
  for (int cc = 0; cc < 2; ++cc) {
    int row = cc * 32 + srow0;
    bf8 kv = *(const bf8*)&Kb[(bh * CS + k0 * 64 + row) * 64 + sch * 8];
    bf8 vv = *(const bf8*)&Vtg[(bh * 64 + row) * CS + k0 * 64 + sch * 8];
    int off = row * 64 + ((sch * 8) ^ ((row & 7) << 3));
    *(bf8*)&KsL[off] = kv;
    *(bf8*)&VsL[off] = vv;
  }
  f16v oa0, oa1;
#pragma unroll
  for (int rr = 0; rr < 16; ++rr) { oa0[rr] = 0.f; oa1[rr] = 0.f; }
  __syncthreads();

  int buf = 0;
  for (int kt = k0; kt < k1; ++kt) {
    // issue kt+1 global loads early (latency hides under this iteration's compute)
    bf8 kr0, kr1, vr0, vr1;
    bool more = (kt + 1) < k1;
    if (more) {
      int r0 = srow0, r1 = srow0 + 32;
      kr0 = *(const bf8*)&Kb[(bh * CS + (kt + 1) * 64 + r0) * 64 + sch * 8];
      kr1 = *(const bf8*)&Kb[(bh * CS + (kt + 1) * 64 + r1) * 64 + sch * 8];
      vr0 = *(const bf8*)&Vtg[(bh * 64 + r0) * CS + (kt + 1) * 64 + sch * 8];
      vr1 = *(const bf8*)&Vtg[(bh * 64 + r1) * CS + (kt + 1) * 64 + sch * 8];
    }
    bool diag = (kt == qt);
    bool active = !(diag && kh == 1 && qh == 0);  // fully-masked wave skips compute
    if (active) {
      // ---- QK: T = K·Q^T over this wave's 32-k strip ----
      f16v ct;
#pragma unroll
      for (int rr = 0; rr < 16; ++rr) ct[rr] = 0.f;
      int kbase = buf * 4096 + (kh * 32 + l31) * 64;
      __builtin_amdgcn_s_setprio(1);
#pragma unroll
      for (int ks = 0; ks < 4; ++ks) {
        bf8 ak = *(const bf8*)&KsL[kbase + ((ks * 16 + g * 8) ^ swz)];
        ct = __builtin_amdgcn_mfma_f32_32x32x16_bf16(ak, qf[ks], ct, 0, 0, 0);
      }
      __builtin_amdgcn_s_setprio(0);
      // ---- exp + causal mask + in-register bf16 pack ----
      bool needmask = diag && (kh == qh);
      unsigned pkA[4], pkB[4];
#pragma unroll
      for (int m = 0; m < 4; ++m) {
        float sv[4];
#pragma unroll
        for (int ii = 0; ii < 4; ++ii) {
          int kloc = ii + 8 * m + 4 * g;
          float ev = exp2f(cg * ct[4 * m + ii]);
          if (needmask && kloc > l31) ev = 0.f;
          sv[ii] = ev;
        }
        pkA[m] = cvt_pk_bf16(sv[0], sv[1]);
        pkB[m] = cvt_pk_bf16(sv[2], sv[3]);
      }
      unsigned sA[4], sB[4];
#pragma unroll
      for (int m = 0; m < 4; ++m) {
        sA[m] = (unsigned)__shfl_xor((int)pkA[m], 32, 64);
        sB[m] = (unsigned)__shfl_xor((int)pkB[m], 32, 64);
      }
      // ---- PV: out^T[e][q] += V'^T[e][k-strip]·S^T[k-strip][q], both e-halves ----
      __builtin_amdgcn_s_setprio(1);
#pragma unroll
      for (int ks2 = 0; ks2 < 2; ++ks2) {
        i4v w;
        w.x = g ? (int)sA[2 * ks2 + 1] : (int)pkA[2 * ks2];
        w.y = g ? (int)sB[2 * ks2 + 1] : (int)pkB[2 * ks2];
        w.z = g ? (int)pkA[2 * ks2 + 1] : (int)sA[2 * ks2];
        w.w = g ? (int)pkB[2 * ks2 + 1] : (int)sB[2 * ks2];
        bf8 bs = *(bf8*)&w;
        int kcol = kh * 32 + ks2 * 16 + g * 8;
        bf8 av0 = *(const bf8*)&VsL[buf * 4096 + l31 * 64 + (kcol ^ swz)];
        oa0 = __builtin_amdgcn_mfma_f32_32x32x16_bf16(av0, bs, oa0, 0, 0, 0);
        bf8 av1 = *(const bf8*)&VsL[buf * 4096 + (32 + l31) * 64 + (kcol ^ swz)];
        oa1 = __builtin_amdgcn_mfma_f32_32x32x16_bf16(av1, bs, oa1, 0, 0, 0);
      }
      __builtin_amdgcn_s_setprio(0);
    }
    // write kt+1 staged regs into the other buffer (prev readers of buf^1 done at last barrier)
    if (more) {
      int r0 = srow0, r1 = srow0 + 32;
      int o0 = (buf ^ 1) * 4096 + r0 * 64 + ((sch * 8) ^ ((r0 & 7) << 3));
      int o1 = (buf ^ 1) * 4096 + r1 * 64 + ((sch * 8) ^ ((r1 & 7) << 3));
      *(bf8*)&KsL[o0] = kr0; *(bf8*)&KsL[o1] = kr1;
      *(bf8*)&VsL[o0] = vr0; *(bf8*)&VsL[o1] = vr1;
    }
    __syncthreads();   // single barrier per k-tile
    buf ^= 1;
  }

  // ---- epilogue: reduce kh=0 + kh=1 partials in LDS (aliased), apply aq, bf16 partial store ----
  if (kh == 0) {
#pragma unroll
    for (int rr = 0; rr < 16; ++rr) {
      int e = (rr & 3) + 8 * (rr >> 2) + 4 * g;
      redf[e * 65 + qh * 32 + l31] = oa0[rr];
      redf[(e + 32) * 65 + qh * 32 + l31] = oa1[rr];
    }
  }
  __syncthreads();
  if (kh == 1) {
#pragma unroll
    for (int rr = 0; rr < 16; ++rr) {
      int e = (rr & 3) + 8 * (rr >> 2) + 4 * g;
      redf[e * 65 + qh * 32 + l31] += oa0[rr];
      redf[(e + 32) * 65 + qh * 32 + l31] += oa1[rr];
    }
  }
  __syncthreads();
  short* Ph = half ? P1 : P0;
  int q = t >> 2, e0 = (t & 3) * 16;
  float aqv = aqg[bh * CS + qt * 64 + q];
  short tmp[16];
#pragma unroll
  for (int jj = 0; jj < 16; ++jj) tmp[jj] = f2bf(redf[(e0 + jj) * 65 + q] * aqv);
  int obase = (bh * CS + qt * 64 + q) * 64 + e0;
  *(bf8*)&Ph[obase] = *(bf8*)&tmp[0];
  *(bf8*)&Ph[obase + 8] = *(bf8*)&tmp[8];
}

// ---------------- output projection (MFMA over both partial buffers, k-split + LDS reduce) ----------------
__global__ __launch_bounds__(256) void k_proj(const short* __restrict__ P0, const short* __restrict__ P1,
                                              const short* __restrict__ Wob, float* __restrict__ out) {
  __shared__ float red[2][32][64];
  int blk = blockIdx.x, t = threadIdx.x;
  int r0 = blk * 32;
  int wid = t >> 6, lane = t & 63, l31 = lane & 31, g = lane >> 5;
  int fh = wid & 1, kh = wid >> 1;
  f16v c; for (int i = 0; i < 16; ++i) c[i] = 0.f;
  int row = r0 + l31;            // 0..4095 over [b][s]
  int b = row >> 11, s = row & 2047;
  int brow = (fh * 32 + l31) * 512;
#pragma unroll
  for (int ks = 0; ks < 16; ++ks) {
    int k0 = kh * 256 + ks * 16 + g * 8;
    int h = k0 >> 6, e = k0 & 63;
    int addr = ((b * 8 + h) * CS + s) * 64 + e;
    bf8 bw = *(const bf8*)&Wob[brow + k0];
    bf8 a0 = *(const bf8*)&P0[addr];
    bf8 a1 = *(const bf8*)&P1[addr];
    c = __builtin_amdgcn_mfma_f32_32x32x16_bf16(a0, bw, c, 0, 0, 0);
    c = __builtin_amdgcn_mfma_f32_32x32x16_bf16(a1, bw, c, 0, 0, 0);
  }
#pragma unroll
  for (int rr = 0; rr < 16; ++rr) {
    int rw = (rr & 3) + 8 * (rr >> 2) + 4 * g;
    red[kh][rw][fh * 32 + l31] = c[rr];
  }
  __syncthreads();
#pragma unroll
  for (int cc = 0; cc < 2; ++cc) {
    int flat = (t * 2 + cc) * 4;
    int rw = flat >> 6, f = flat & 63;
    f4v a = *(f4v*)&red[0][rw][f];
    f4v bsum = *(f4v*)&red[1][rw][f];
    f4v sum = a + bsum;
    *(f4v*)&out[(r0 + rw) * 64 + f] = sum;
  }
}

extern "C" void kernel_launch(void* const* d_in, const int* in_sizes, int n_in,
                              void* d_out, int out_size, void* d_ws, size_t ws_size,
                              hipStream_t stream) {
  const float* x     = (const float*)d_in[0];
  const float* ln_w  = (const float*)d_in[1];
  const float* Wq    = (const float*)d_in[2];
  const float* Wk    = (const float*)d_in[3];
  const float* Wv    = (const float*)d_in[4];
  const float* Wo    = (const float*)d_in[5];
  const float* gamma = (const float*)d_in[6];
  float* out = (float*)d_out;

  char* w = (char*)d_ws;
  short* Qb  = (short*)w;                               // 4 MB
  short* Kb  = (short*)(w + 4194304);                   // 4 MB
  short* Vt  = (short*)(w + 2 * 4194304);               // 4 MB
  float* aqg = (float*)(w + 3 * 4194304);               // 128 KB
  short* P0  = (short*)(w + 3 * 4194304 + 131072);      // 4 MB
  short* P1  = (short*)(w + 4 * 4194304 + 131072);      // 4 MB
  short* WtQ = (short*)(w + 5 * 4194304 + 131072);      // 64 KB x4
  short* WtK = WtQ + 32768;
  short* WtV = WtK + 32768;
  short* Wob = WtV + 32768;

  hipLaunchKernelGGL(k_prep, dim3(32),   dim3(256), 0, stream, Wq, Wk, Wv, Wo, WtQ, WtK, WtV, Wob);
  hipLaunchKernelGGL(k_qkv,  dim3(512),  dim3(256), 0, stream, x, ln_w, WtQ, WtK, WtV, gamma, Qb, Kb, Vt, aqg);
  hipLaunchKernelGGL(k_attn, dim3(1024), dim3(256), 0, stream, Qb, Kb, Vt, aqg, gamma, P0, P1);
  hipLaunchKernelGGL(k_proj, dim3(128),  dim3(256), 0, stream, P0, P1, Wob, out);
}